// Round 1
// baseline (107281.396 us; speedup 1.0000x reference)
//
#include <hip/hip_runtime.h>
#include <cstdint>
#include <cstddef>

#define T_LEN 4096

typedef _Float16 half8 __attribute__((ext_vector_type(8)));
typedef float floatx4 __attribute__((ext_vector_type(4)));

#define MFMA16(a, b, c) __builtin_amdgcn_mfma_f32_16x16x32_f16((a), (b), (c), 0, 0, 0)

// ---- workspace layout (bytes) ----
static constexpr size_t OFF_W1  = 0;                          // [2048][576] f16  (k<64: w_ih1, k>=64: w_hh1)
static constexpr size_t SZ_W1   = (size_t)2048 * 576 * 2;
static constexpr size_t OFF_W2  = OFF_W1 + SZ_W1;             // [2048][1024] f16 (k<512: w_ih2, k>=512: w_hh2)
static constexpr size_t SZ_W2   = (size_t)2048 * 1024 * 2;
static constexpr size_t OFF_H12 = OFF_W2 + SZ_W2;             // [2][128][1024] f16 : [b][0:512]=h1, [512:1024]=h2
static constexpr size_t SZ_H12  = (size_t)2 * 128 * 1024 * 2;
static constexpr size_t OFF_B1  = OFF_H12 + SZ_H12;           // [2048] f32 combined bias layer1
static constexpr size_t OFF_B2  = OFF_B1 + 2048 * 4;          // [2048] f32 combined bias layer2
static constexpr size_t OFF_CNT = OFF_B2 + 2048 * 4;          // 256 ints: [g*16]=SA, [128+g*16]=SB

__global__ void setup_kernel(const float* __restrict__ w_ih1, const float* __restrict__ w_hh1,
                             const float* __restrict__ b_ih1, const float* __restrict__ b_hh1,
                             const float* __restrict__ w_ih2, const float* __restrict__ w_hh2,
                             const float* __restrict__ b_ih2, const float* __restrict__ b_hh2,
                             _Float16* __restrict__ W1f, _Float16* __restrict__ W2f,
                             _Float16* __restrict__ h12, float* __restrict__ bias1,
                             float* __restrict__ bias2, int* __restrict__ cnt)
{
  const int idx = blockIdx.x * blockDim.x + threadIdx.x;
  const int str = gridDim.x * blockDim.x;
  for (int i = idx; i < 2048 * 576; i += str) {
    const int r = i / 576, k = i - r * 576;
    const float v = (k < 64) ? w_ih1[r * 64 + k] : w_hh1[r * 512 + (k - 64)];
    W1f[i] = (_Float16)v;
  }
  for (int i = idx; i < 2048 * 1024; i += str) {
    const int r = i >> 10, k = i & 1023;
    const float v = (k < 512) ? w_ih2[r * 512 + k] : w_hh2[r * 512 + (k - 512)];
    W2f[i] = (_Float16)v;
  }
  for (int i = idx; i < 2 * 128 * 1024; i += str) h12[i] = (_Float16)0.0f;
  for (int i = idx; i < 2048; i += str) {
    bias1[i] = b_ih1[i] + b_hh1[i];
    bias2[i] = b_ih2[i] + b_hh2[i];
  }
  for (int i = idx; i < 256; i += str) cnt[i] = 0;
}

__device__ __forceinline__ float sigm(float v) { return 1.0f / (1.0f + __expf(-v)); }
__device__ __forceinline__ float tanh_fast(float v) {
  v = fminf(fmaxf(v, -15.0f), 15.0f);
  const float e = __expf(2.0f * v);
  return (e - 1.0f) / (e + 1.0f);
}

// Grid: 256 blocks x 512 threads, cooperative. block = (group g = blockIdx%8 -> 16 batch rows,
// jj = blockIdx/8 -> 16 hidden units). 8 waves: wave = (nb = gate 0..3, kh = K-half 0..1).
__global__ __launch_bounds__(512, 1)
void lstm_kernel(const float* __restrict__ x,
                 const _Float16* __restrict__ W1f,
                 const _Float16* __restrict__ W2f,
                 const float* __restrict__ bias1,
                 const float* __restrict__ bias2,
                 const float* __restrict__ w_out,
                 const float* __restrict__ b_out,
                 _Float16* __restrict__ h12,
                 int* __restrict__ cnt,
                 float* __restrict__ out)
{
  __shared__ _Float16 W2s[64 * 1032];      // 64 gate-rows x 1024 K, stride 1032 (pad vs bank conflicts)
  __shared__ float gbuf[2][4][16][20];     // [kh][gate][unit n][batch m(+pad)]
  __shared__ float ybuf[32][9];            // y partials: [16b x 2o][8 kparts]

  const int wg   = blockIdx.x;
  const int g    = wg & 7;                 // group (intended XCD via %8 dispatch heuristic)
  const int jj   = wg >> 3;                // 0..31 unit-block
  const int B0   = g * 16;
  const int U0   = jj * 16;
  const int tid  = threadIdx.x;
  const int lane = tid & 63;
  const int wv   = tid >> 6;
  const int nb   = wv & 3;                 // gate block
  const int kh   = wv >> 2;                // K half
  const int lrow = lane & 15;              // A: batch row / B: unit row
  const int quad = lane >> 4;

  int* cntA = cnt + g * 16;
  int* cntB = cnt + 128 + g * 16;

  // Stage W2 slice into LDS once (rows r = gate*16 + u  <->  global row gate*512 + U0 + u)
  for (int c = tid; c < 64 * 128; c += 512) {
    const int r = c >> 7;
    const int kc = (c & 127) << 3;
    const int grow = ((r >> 4) << 9) + U0 + (r & 15);
    *(half8*)(&W2s[r * 1032 + kc]) = *(const half8*)(&W2f[(size_t)grow * 1024 + kc]);
  }

  float c1 = 0.0f, c2 = 0.0f;              // cell state lives in registers (threads 0..255)
  float bs1[4] = {0.f, 0.f, 0.f, 0.f};
  float bs2[4] = {0.f, 0.f, 0.f, 0.f};
  const int eb = tid >> 4;                 // elem thread: batch
  const int eu = tid & 15;                 // elem thread: unit
  if (tid < 256) {
#pragma unroll
    for (int gg = 0; gg < 4; ++gg) {
      bs1[gg] = bias1[gg * 512 + U0 + eu];
      bs2[gg] = bias2[gg * 512 + U0 + eu];
    }
  }
  __syncthreads();

  const _Float16* W1row = W1f + (size_t)(nb * 512 + U0 + lrow) * 576 + quad * 8;
  const _Float16* W2row = W2s + (nb * 16 + lrow) * 1032 + quad * 8;
  const float*    xrow  = x + (size_t)(B0 + lrow) * (T_LEN * 64) + quad * 8;

#pragma unroll 1
  for (int t = 0; t < T_LEN; ++t) {
    const int s = t & 1;
    const _Float16* hp = h12 + (s ^ 1) * (128 * 1024);   // state(t-1)
    _Float16*       hc = h12 + s * (128 * 1024);         // state(t)

    // ================= Phase A: gates1 = [x_t | h1(t-1)] @ W1^T =================
    floatx4 acc0 = {0.f, 0.f, 0.f, 0.f};
    floatx4 acc1 = {0.f, 0.f, 0.f, 0.f};
    {
      const float*    xr = xrow + (size_t)t * 64;
      const _Float16* ar = hp + (B0 + lrow) * 1024 + quad * 8;
      if (kh == 0) {
#pragma unroll
        for (int kb = 0; kb < 9; ++kb) {
          const int k0 = kb * 32;
          half8 av;
          if (kb < 2) {                           // x part (fp32 -> fp16)
            const floatx4 x0 = *(const floatx4*)(xr + k0);
            const floatx4 x1 = *(const floatx4*)(xr + k0 + 4);
            av[0] = (_Float16)x0[0]; av[1] = (_Float16)x0[1];
            av[2] = (_Float16)x0[2]; av[3] = (_Float16)x0[3];
            av[4] = (_Float16)x1[0]; av[5] = (_Float16)x1[1];
            av[6] = (_Float16)x1[2]; av[7] = (_Float16)x1[3];
          } else {
            av = *(const half8*)(ar + (k0 - 64));
          }
          const half8 bv = *(const half8*)(W1row + k0);
          if (kb & 1) acc1 = MFMA16(av, bv, acc1);
          else        acc0 = MFMA16(av, bv, acc0);
        }
      } else {
#pragma unroll
        for (int kb = 9; kb < 18; ++kb) {
          const int k0 = kb * 32;
          const half8 av = *(const half8*)(ar + (k0 - 64));
          const half8 bv = *(const half8*)(W1row + k0);
          if (kb & 1) acc1 = MFMA16(av, bv, acc1);
          else        acc0 = MFMA16(av, bv, acc0);
        }
      }
    }
    {
      const floatx4 a = acc0 + acc1;   // C layout: n = lane&15, m = quad*4 + reg
      *(floatx4*)(&gbuf[kh][nb][lrow][quad * 4]) = a;
    }
    __syncthreads();
    if (tid < 256) {
      const float s0 = gbuf[0][0][eu][eb] + gbuf[1][0][eu][eb] + bs1[0];
      const float s1 = gbuf[0][1][eu][eb] + gbuf[1][1][eu][eb] + bs1[1];
      const float s2 = gbuf[0][2][eu][eb] + gbuf[1][2][eu][eb] + bs1[2];
      const float s3 = gbuf[0][3][eu][eb] + gbuf[1][3][eu][eb] + bs1[3];
      const float iv = sigm(s0), fv = sigm(s1);
      const float gv = tanh_fast(s2), ov = sigm(s3);
      c1 = fv * c1 + iv * gv;
      const float hv = ov * tanh_fast(c1);
      hc[(B0 + eb) * 1024 + (U0 + eu)] = (_Float16)hv;
    }
    __syncthreads();                                   // h1 stores drained (vmcnt0)
    if (tid == 0) { __threadfence(); atomicAdd(cntA, 1); }   // arrive SA_t

    // ================= Phase B: gates2 = [h1(t) | h2(t-1)] @ W2^T =================
    floatx4 bcc0 = {0.f, 0.f, 0.f, 0.f};
    floatx4 bcc1 = {0.f, 0.f, 0.f, 0.f};
    // wait SB_{t-1} (h2(t-1) group-visible) -- satisfied ~a whole phase ago
    if (tid == 0) {
      while (__hip_atomic_load(cntB, __ATOMIC_RELAXED, __HIP_MEMORY_SCOPE_AGENT) < 32 * t)
        __builtin_amdgcn_s_sleep(2);
      __threadfence();
    }
    __syncthreads();
    {
      const _Float16* a2 = hp + (B0 + lrow) * 1024 + 512 + quad * 8;   // h2(t-1)
#pragma unroll
      for (int kb = 0; kb < 8; ++kb) {
        const int kk = (kh * 8 + kb) * 32;
        const half8 av = *(const half8*)(a2 + kk);
        const half8 bv = *(const half8*)(W2row + 512 + kk);
        if (kb & 1) bcc1 = MFMA16(av, bv, bcc1);
        else        bcc0 = MFMA16(av, bv, bcc0);
      }
    }
    // wait SA_t (h1(t) group-visible) -- hidden behind the h2 half above
    if (tid == 0) {
      while (__hip_atomic_load(cntA, __ATOMIC_RELAXED, __HIP_MEMORY_SCOPE_AGENT) < 32 * (t + 1))
        __builtin_amdgcn_s_sleep(2);
      __threadfence();
    }
    __syncthreads();
    {
      const _Float16* a1 = hc + (B0 + lrow) * 1024 + quad * 8;         // h1(t)
#pragma unroll
      for (int kb = 0; kb < 8; ++kb) {
        const int kk = (kh * 8 + kb) * 32;
        const half8 av = *(const half8*)(a1 + kk);
        const half8 bv = *(const half8*)(W2row + kk);
        if (kb & 1) bcc1 = MFMA16(av, bv, bcc1);
        else        bcc0 = MFMA16(av, bv, bcc0);
      }
    }
    {
      const floatx4 a = bcc0 + bcc1;
      *(floatx4*)(&gbuf[kh][nb][lrow][quad * 4]) = a;
    }
    __syncthreads();
    if (tid < 256) {
      const float s0 = gbuf[0][0][eu][eb] + gbuf[1][0][eu][eb] + bs2[0];
      const float s1 = gbuf[0][1][eu][eb] + gbuf[1][1][eu][eb] + bs2[1];
      const float s2 = gbuf[0][2][eu][eb] + gbuf[1][2][eu][eb] + bs2[2];
      const float s3 = gbuf[0][3][eu][eb] + gbuf[1][3][eu][eb] + bs2[3];
      const float iv = sigm(s0), fv = sigm(s1);
      const float gv = tanh_fast(s2), ov = sigm(s3);
      c2 = fv * c2 + iv * gv;
      const float hv = ov * tanh_fast(c2);
      hc[(B0 + eb) * 1024 + 512 + (U0 + eu)] = (_Float16)hv;
    } else if (t > 0) {
      // y(t-1) partials: exact fp32 dot of h2(t-1) (fp16) with w_out rows jj*2, jj*2+1
      const int tt  = tid - 256;
      const int dot = tt >> 3;
      const int kp  = tt & 7;
      const int b   = dot & 15;
      const int oo  = dot >> 4;
      const int oi  = jj * 2 + oo;
      const _Float16* hr = hp + (B0 + b) * 1024 + 512 + kp * 64;
      const float*    wr = w_out + oi * 512 + kp * 64;
      float sacc = 0.f;
#pragma unroll
      for (int kc = 0; kc < 8; ++kc) {
        const half8  hv8 = *(const half8*)(hr + kc * 8);
        const floatx4 w0 = *(const floatx4*)(wr + kc * 8);
        const floatx4 w1 = *(const floatx4*)(wr + kc * 8 + 4);
        sacc += (float)hv8[0] * w0[0] + (float)hv8[1] * w0[1]
              + (float)hv8[2] * w0[2] + (float)hv8[3] * w0[3]
              + (float)hv8[4] * w1[0] + (float)hv8[5] * w1[1]
              + (float)hv8[6] * w1[2] + (float)hv8[7] * w1[3];
      }
      ybuf[dot][kp] = sacc;
    }
    __syncthreads();                                   // h2 stores drained
    if (t > 0 && tid < 32) {
      const int b  = tid & 15;
      const int oo = tid >> 4;
      const int oi = jj * 2 + oo;
      float sacc = b_out[oi];
#pragma unroll
      for (int kp = 0; kp < 8; ++kp) sacc += ybuf[tid][kp];
      out[((size_t)(B0 + b) * T_LEN + (t - 1)) * 64 + oi] = sacc;
    }
    if (tid == 0) { __threadfence(); atomicAdd(cntB, 1); }   // arrive SB_t
  }

  // ---- tail: y(T-1) ----
  if (tid == 0) {
    while (__hip_atomic_load(cntB, __ATOMIC_RELAXED, __HIP_MEMORY_SCOPE_AGENT) < 32 * T_LEN)
      __builtin_amdgcn_s_sleep(2);
    __threadfence();
  }
  __syncthreads();
  {
    const _Float16* hl = h12 + ((T_LEN - 1) & 1) * (128 * 1024);
    if (tid >= 256) {
      const int tt  = tid - 256;
      const int dot = tt >> 3;
      const int kp  = tt & 7;
      const int b   = dot & 15;
      const int oo  = dot >> 4;
      const int oi  = jj * 2 + oo;
      const _Float16* hr = hl + (B0 + b) * 1024 + 512 + kp * 64;
      const float*    wr = w_out + oi * 512 + kp * 64;
      float sacc = 0.f;
#pragma unroll
      for (int kc = 0; kc < 8; ++kc) {
        const half8  hv8 = *(const half8*)(hr + kc * 8);
        const floatx4 w0 = *(const floatx4*)(wr + kc * 8);
        const floatx4 w1 = *(const floatx4*)(wr + kc * 8 + 4);
        sacc += (float)hv8[0] * w0[0] + (float)hv8[1] * w0[1]
              + (float)hv8[2] * w0[2] + (float)hv8[3] * w0[3]
              + (float)hv8[4] * w1[0] + (float)hv8[5] * w1[1]
              + (float)hv8[6] * w1[2] + (float)hv8[7] * w1[3];
      }
      ybuf[dot][kp] = sacc;
    }
    __syncthreads();
    if (tid < 32) {
      const int b  = tid & 15;
      const int oo = tid >> 4;
      const int oi = jj * 2 + oo;
      float sacc = b_out[oi];
#pragma unroll
      for (int kp = 0; kp < 8; ++kp) sacc += ybuf[tid][kp];
      out[((size_t)(B0 + b) * T_LEN + (T_LEN - 1)) * 64 + oi] = sacc;
    }
  }
}

extern "C" void kernel_launch(void* const* d_in, const int* in_sizes, int n_in,
                              void* d_out, int out_size, void* d_ws, size_t ws_size,
                              hipStream_t stream) {
  (void)in_sizes; (void)n_in; (void)out_size; (void)ws_size;

  const float* x      = (const float*)d_in[0];
  const float* w_ih1  = (const float*)d_in[1];
  const float* w_hh1  = (const float*)d_in[2];
  const float* b_ih1  = (const float*)d_in[3];
  const float* b_hh1  = (const float*)d_in[4];
  const float* w_ih2  = (const float*)d_in[5];
  const float* w_hh2  = (const float*)d_in[6];
  const float* b_ih2  = (const float*)d_in[7];
  const float* b_hh2  = (const float*)d_in[8];
  const float* w_out  = (const float*)d_in[9];
  const float* b_out  = (const float*)d_in[10];

  char* ws = (char*)d_ws;
  _Float16* W1f   = (_Float16*)(ws + OFF_W1);
  _Float16* W2f   = (_Float16*)(ws + OFF_W2);
  _Float16* h12   = (_Float16*)(ws + OFF_H12);
  float*    bias1 = (float*)(ws + OFF_B1);
  float*    bias2 = (float*)(ws + OFF_B2);
  int*      cnt   = (int*)(ws + OFF_CNT);
  float*    outp  = (float*)d_out;

  hipLaunchKernelGGL(setup_kernel, dim3(1024), dim3(256), 0, stream,
                     w_ih1, w_hh1, b_ih1, b_hh1, w_ih2, w_hh2, b_ih2, b_hh2,
                     W1f, W2f, h12, bias1, bias2, cnt);

  void* args[] = { (void*)&x, (void*)&W1f, (void*)&W2f, (void*)&bias1, (void*)&bias2,
                   (void*)&w_out, (void*)&b_out, (void*)&h12, (void*)&cnt, (void*)&outp };
  hipLaunchCooperativeKernel((void*)lstm_kernel, dim3(256), dim3(512), args, 0, stream);
}

// Round 2
// 41979.007 us; speedup vs baseline: 2.5556x; 2.5556x over previous
//
#include <hip/hip_runtime.h>
#include <cstdint>
#include <cstddef>

#define T_LEN 4096

typedef _Float16 half8 __attribute__((ext_vector_type(8)));
typedef float floatx4 __attribute__((ext_vector_type(4)));
typedef unsigned long long u64;

#define MFMA16(a, b, c) __builtin_amdgcn_mfma_f32_16x16x32_f16((a), (b), (c), 0, 0, 0)
#define SCOPE_AGENT __HIP_MEMORY_SCOPE_AGENT

// ---- workspace layout (bytes) ----
static constexpr size_t OFF_W1  = 0;                          // [2048][576] f16  (k<64: w_ih1, k>=64: w_hh1)
static constexpr size_t SZ_W1   = (size_t)2048 * 576 * 2;
static constexpr size_t OFF_W2  = OFF_W1 + SZ_W1;             // [2048][1024] f16 (k<512: w_ih2, k>=512: w_hh2)
static constexpr size_t SZ_W2   = (size_t)2048 * 1024 * 2;
static constexpr size_t OFF_H12 = OFF_W2 + SZ_W2;             // [2][128][1024] f16 : [b][0:512]=h1, [512:1024]=h2
static constexpr size_t SZ_H12  = (size_t)2 * 128 * 1024 * 2;
static constexpr size_t OFF_B1  = OFF_H12 + SZ_H12;           // [2048] f32 combined bias layer1
static constexpr size_t OFF_B2  = OFF_B1 + 2048 * 4;          // [2048] f32 combined bias layer2
static constexpr size_t OFF_CNT = OFF_B2 + 2048 * 4;          // 128 ints: cnt[g*16] per group

__global__ void setup_kernel(const float* __restrict__ w_ih1, const float* __restrict__ w_hh1,
                             const float* __restrict__ b_ih1, const float* __restrict__ b_hh1,
                             const float* __restrict__ w_ih2, const float* __restrict__ w_hh2,
                             const float* __restrict__ b_ih2, const float* __restrict__ b_hh2,
                             _Float16* __restrict__ W1f, _Float16* __restrict__ W2f,
                             _Float16* __restrict__ h12, float* __restrict__ bias1,
                             float* __restrict__ bias2, int* __restrict__ cnt)
{
  const int idx = blockIdx.x * blockDim.x + threadIdx.x;
  const int str = gridDim.x * blockDim.x;
  for (int i = idx; i < 2048 * 576; i += str) {
    const int r = i / 576, k = i - r * 576;
    const float v = (k < 64) ? w_ih1[r * 64 + k] : w_hh1[r * 512 + (k - 64)];
    W1f[i] = (_Float16)v;
  }
  for (int i = idx; i < 2048 * 1024; i += str) {
    const int r = i >> 10, k = i & 1023;
    const float v = (k < 512) ? w_ih2[r * 512 + k] : w_hh2[r * 512 + (k - 512)];
    W2f[i] = (_Float16)v;
  }
  for (int i = idx; i < 2 * 128 * 1024; i += str) h12[i] = (_Float16)0.0f;
  for (int i = idx; i < 2048; i += str) {
    bias1[i] = b_ih1[i] + b_hh1[i];
    bias2[i] = b_ih2[i] + b_hh2[i];
  }
  for (int i = idx; i < 128; i += str) cnt[i] = 0;
}

__device__ __forceinline__ float sigm(float v) { return 1.0f / (1.0f + __expf(-v)); }
__device__ __forceinline__ float tanh_fast(float v) {
  v = fminf(fmaxf(v, -15.0f), 15.0f);
  const float e = __expf(2.0f * v);
  return (e - 1.0f) / (e + 1.0f);
}

__device__ __forceinline__ u64 ld_a_u64(const u64* p) {
  return __hip_atomic_load(p, __ATOMIC_RELAXED, SCOPE_AGENT);
}
__device__ __forceinline__ void st_a_u64(u64* p, u64 v) {
  __hip_atomic_store(p, v, __ATOMIC_RELAXED, SCOPE_AGENT);
}

// Grid: 256 WGs x 512 thr, cooperative. WG = (g = blockIdx%8 -> 16 batch rows, jj = blockIdx/8 -> 16 units).
// Superstep s: waves 0-3 compute gates1(s) [s<T]; waves 4-7 compute gates2(s-1) [1<=s<=T]; y(s-2) [s>=2].
// ONE group sync per superstep; all h-state via relaxed agent atomics (sc1, L2-bypass) -> no cache fences.
__global__ __launch_bounds__(512, 1)
void lstm_kernel(const float* __restrict__ x,
                 const _Float16* __restrict__ W1f,
                 const _Float16* __restrict__ W2f,
                 const float* __restrict__ bias1,
                 const float* __restrict__ bias2,
                 const float* __restrict__ w_out,
                 const float* __restrict__ b_out,
                 _Float16* __restrict__ h12,
                 int* __restrict__ cnt,
                 float* __restrict__ out)
{
  __shared__ __align__(16) _Float16 W2s[64 * 520];        // h1-half of W2 rows (gate*16+u), K 0..511, pad->520
  __shared__ __align__(16) _Float16 hstage[2][16][520];   // [0]=h1(s-1), [1]=h2(s-2); pad->520
  __shared__ float gbuf[2][4][16][20];                    // [layer][gate][unit n][batch m(+pad)]
  __shared__ float ybuf[32][9];
  __shared__ __align__(16) _Float16 hpack[2][16][16];     // [layer][batch][unit]

  const int wg   = blockIdx.x;
  const int g    = wg & 7;
  const int jj   = wg >> 3;
  const int B0   = g * 16;
  const int U0   = jj * 16;
  const int tid  = threadIdx.x;
  const int lane = tid & 63;
  const int wv   = tid >> 6;
  const int lrow = lane & 15;
  const int quad = lane >> 4;

  int* cntS = cnt + g * 16;
  u64* hb   = (u64*)h12;     // u64 view of h12 (4 f16 per u64)

  // ---- stage h1-half of W2 into LDS (once) ----
  for (int c = tid; c < 64 * 128; c += 512) {
    const int r  = c >> 7;
    const int cc = c & 127;
    const int grow = ((r >> 4) << 9) + U0 + (r & 15);
    *(u64*)&W2s[r * 520 + cc * 4] = *(const u64*)&W2f[(size_t)grow * 1024 + cc * 4];
  }

  float c1 = 0.0f, c2 = 0.0f;
  float bs1[4] = {0.f, 0.f, 0.f, 0.f};
  float bs2[4] = {0.f, 0.f, 0.f, 0.f};
  if (tid < 256) {
    const int eu = tid & 15;
#pragma unroll
    for (int gg = 0; gg < 4; ++gg) bs1[gg] = bias1[gg * 512 + U0 + eu];
  } else {
    const int eu = tid & 15;
#pragma unroll
    for (int gg = 0; gg < 4; ++gg) bs2[gg] = bias2[gg * 512 + U0 + eu];
  }

  const _Float16* w1r = W1f + (size_t)(((wv & 3) * 512 + U0 + lrow)) * 576 + quad * 8;
  const _Float16* w2r = W2f + (size_t)(((wv & 3) * 512 + U0 + lrow)) * 1024 + 512 + quad * 8;
  const _Float16* w2l = W2s + ((wv & 3) * 16 + lrow) * 520 + quad * 8;
  const float*    xrw = x + (size_t)(B0 + lrow) * (T_LEN * 64) + quad * 8;

#pragma unroll 1
  for (int s = 0; s < T_LEN + 2; ++s) {
    const int p1 = s & 1;                      // parity of h1(s); h1(s-1) at p1^1; h2(s-2) at p1

    // ---- wait for superstep s-1 publications, then stage h-state into LDS ----
    if (tid == 0) {
      while (__hip_atomic_load(cntS, __ATOMIC_RELAXED, SCOPE_AGENT) < 32 * s)
        __builtin_amdgcn_s_sleep(1);
    }
    __syncthreads();

    {
      const u64* h1src = hb + (size_t)(p1 ^ 1) * 32768;
      const u64* h2src = hb + (size_t)p1 * 32768;
#pragma unroll
      for (int i = 0; i < 8; ++i) {
        const int idx  = tid + i * 512;        // 0..4095
        const int half = idx >> 11;
        const int r    = (idx >> 7) & 15;
        const int cc   = idx & 127;
        u64 v;
        if (half == 0) v = ld_a_u64(h1src + (size_t)(B0 + r) * 256 + cc);
        else           v = ld_a_u64(h2src + (size_t)(B0 + r) * 256 + 128 + cc);
        *(u64*)&hstage[half][r][cc * 4] = v;
      }
    }
    __syncthreads();

    // ---- MFMA phase ----
    if (wv < 4) {
      if (s < T_LEN) {
        floatx4 a0 = {0.f, 0.f, 0.f, 0.f};
        floatx4 a1 = {0.f, 0.f, 0.f, 0.f};
        const float* xr = xrw + (size_t)s * 64;
#pragma unroll
        for (int kb = 0; kb < 2; ++kb) {
          const floatx4 x0 = *(const floatx4*)(xr + kb * 32);
          const floatx4 x1 = *(const floatx4*)(xr + kb * 32 + 4);
          half8 av;
          av[0] = (_Float16)x0[0]; av[1] = (_Float16)x0[1];
          av[2] = (_Float16)x0[2]; av[3] = (_Float16)x0[3];
          av[4] = (_Float16)x1[0]; av[5] = (_Float16)x1[1];
          av[6] = (_Float16)x1[2]; av[7] = (_Float16)x1[3];
          const half8 bv = *(const half8*)(w1r + kb * 32);
          if (kb & 1) a1 = MFMA16(av, bv, a1);
          else        a0 = MFMA16(av, bv, a0);
        }
#pragma unroll
        for (int kb = 2; kb < 18; ++kb) {
          const half8 av = *(const half8*)(&hstage[0][lrow][(kb - 2) * 32 + quad * 8]);
          const half8 bv = *(const half8*)(w1r + kb * 32);
          if (kb & 1) a1 = MFMA16(av, bv, a1);
          else        a0 = MFMA16(av, bv, a0);
        }
        const floatx4 a = a0 + a1;
        *(floatx4*)(&gbuf[0][wv & 3][lrow][quad * 4]) = a;
      }
    } else {
      if (s >= 1 && s <= T_LEN) {
        floatx4 a0 = {0.f, 0.f, 0.f, 0.f};
        floatx4 a1 = {0.f, 0.f, 0.f, 0.f};
#pragma unroll
        for (int kb = 0; kb < 16; ++kb) {      // h1(s-1) x W2s(LDS)
          const half8 av = *(const half8*)(&hstage[0][lrow][kb * 32 + quad * 8]);
          const half8 bv = *(const half8*)(w2l + kb * 32);
          if (kb & 1) a1 = MFMA16(av, bv, a1);
          else        a0 = MFMA16(av, bv, a0);
        }
#pragma unroll
        for (int kb = 0; kb < 16; ++kb) {      // h2(s-2) x W2f h2-half (L2-hot global)
          const half8 av = *(const half8*)(&hstage[1][lrow][kb * 32 + quad * 8]);
          const half8 bv = *(const half8*)(w2r + kb * 32);
          if (kb & 1) a1 = MFMA16(av, bv, a1);
          else        a0 = MFMA16(av, bv, a0);
        }
        const floatx4 a = a0 + a1;
        *(floatx4*)(&gbuf[1][wv & 3][lrow][quad * 4]) = a;
      }
    }
    __syncthreads();

    // ---- elementwise + y partials ----
    if (tid < 256) {
      if (s < T_LEN) {
        const int eb = tid >> 4, eu = tid & 15;
        const float s0 = gbuf[0][0][eu][eb] + bs1[0];
        const float s1 = gbuf[0][1][eu][eb] + bs1[1];
        const float s2 = gbuf[0][2][eu][eb] + bs1[2];
        const float s3 = gbuf[0][3][eu][eb] + bs1[3];
        const float iv = sigm(s0), fv = sigm(s1);
        const float gv = tanh_fast(s2), ov = sigm(s3);
        c1 = fv * c1 + iv * gv;
        hpack[0][eb][eu] = (_Float16)(ov * tanh_fast(c1));
      }
      if (s >= 2) {                            // y(s-2) partials from hstage[1]=h2(s-2)
        const int dot = tid >> 3;
        const int kp  = tid & 7;
        const int b   = dot & 15;
        const int oo  = dot >> 4;
        const int oi  = jj * 2 + oo;
        const float* wr = w_out + oi * 512 + kp * 64;
        float sacc = 0.f;
#pragma unroll
        for (int kc = 0; kc < 8; ++kc) {
          const half8  hv8 = *(const half8*)(&hstage[1][b][kp * 64 + kc * 8]);
          const floatx4 w0 = *(const floatx4*)(wr + kc * 8);
          const floatx4 w1 = *(const floatx4*)(wr + kc * 8 + 4);
          sacc += (float)hv8[0] * w0[0] + (float)hv8[1] * w0[1]
                + (float)hv8[2] * w0[2] + (float)hv8[3] * w0[3]
                + (float)hv8[4] * w1[0] + (float)hv8[5] * w1[1]
                + (float)hv8[6] * w1[2] + (float)hv8[7] * w1[3];
        }
        ybuf[dot][kp] = sacc;
      }
    } else {
      if (s >= 1 && s <= T_LEN) {
        const int tt = tid - 256;
        const int eb = tt >> 4, eu = tt & 15;
        const float s0 = gbuf[1][0][eu][eb] + bs2[0];
        const float s1 = gbuf[1][1][eu][eb] + bs2[1];
        const float s2 = gbuf[1][2][eu][eb] + bs2[2];
        const float s3 = gbuf[1][3][eu][eb] + bs2[3];
        const float iv = sigm(s0), fv = sigm(s1);
        const float gv = tanh_fast(s2), ov = sigm(s3);
        c2 = fv * c2 + iv * gv;
        hpack[1][eb][eu] = (_Float16)(ov * tanh_fast(c2));
      }
    }
    __syncthreads();

    // ---- publish h-state (sc1 stores), y output, then arrive ----
    if (tid >= 64 && tid < 128) {
      if (s < T_LEN) {                         // h1(s) -> parity p1
        const int i = tid - 64, eb = i >> 2, c4 = i & 3;
        const u64 v = *(const u64*)&hpack[0][eb][c4 * 4];
        st_a_u64(hb + (size_t)p1 * 32768 + (size_t)(B0 + eb) * 256 + (U0 >> 2) + c4, v);
      }
    } else if (tid >= 128 && tid < 192) {
      if (s >= 1 && s <= T_LEN) {              // h2(s-1) -> parity p1^1
        const int i = tid - 128, eb = i >> 2, c4 = i & 3;
        const u64 v = *(const u64*)&hpack[1][eb][c4 * 4];
        st_a_u64(hb + (size_t)(p1 ^ 1) * 32768 + (size_t)(B0 + eb) * 256 + 128 + (U0 >> 2) + c4, v);
      }
    } else if (tid < 32) {
      if (s >= 2) {                            // y(s-2) final reduce + store
        const int b  = tid & 15;
        const int oo = tid >> 4;
        const int oi = jj * 2 + oo;
        float sacc = b_out[oi];
#pragma unroll
        for (int kp = 0; kp < 8; ++kp) sacc += ybuf[tid][kp];
        out[((size_t)(B0 + b) * T_LEN + (s - 2)) * 64 + oi] = sacc;
      }
    }
    __syncthreads();                           // drains each wave's sc1 stores (vmcnt 0)
    if (tid == 0 && s <= T_LEN) {
      __hip_atomic_fetch_add(cntS, 1, __ATOMIC_RELAXED, SCOPE_AGENT);
    }
  }
}

extern "C" void kernel_launch(void* const* d_in, const int* in_sizes, int n_in,
                              void* d_out, int out_size, void* d_ws, size_t ws_size,
                              hipStream_t stream) {
  (void)in_sizes; (void)n_in; (void)out_size; (void)ws_size;

  const float* x      = (const float*)d_in[0];
  const float* w_ih1  = (const float*)d_in[1];
  const float* w_hh1  = (const float*)d_in[2];
  const float* b_ih1  = (const float*)d_in[3];
  const float* b_hh1  = (const float*)d_in[4];
  const float* w_ih2  = (const float*)d_in[5];
  const float* w_hh2  = (const float*)d_in[6];
  const float* b_ih2  = (const float*)d_in[7];
  const float* b_hh2  = (const float*)d_in[8];
  const float* w_out  = (const float*)d_in[9];
  const float* b_out  = (const float*)d_in[10];

  char* ws = (char*)d_ws;
  _Float16* W1f   = (_Float16*)(ws + OFF_W1);
  _Float16* W2f   = (_Float16*)(ws + OFF_W2);
  _Float16* h12   = (_Float16*)(ws + OFF_H12);
  float*    bias1 = (float*)(ws + OFF_B1);
  float*    bias2 = (float*)(ws + OFF_B2);
  int*      cnt   = (int*)(ws + OFF_CNT);
  float*    outp  = (float*)d_out;

  hipLaunchKernelGGL(setup_kernel, dim3(1024), dim3(256), 0, stream,
                     w_ih1, w_hh1, b_ih1, b_hh1, w_ih2, w_hh2, b_ih2, b_hh2,
                     W1f, W2f, h12, bias1, bias2, cnt);

  void* args[] = { (void*)&x, (void*)&W1f, (void*)&W2f, (void*)&bias1, (void*)&bias2,
                   (void*)&w_out, (void*)&b_out, (void*)&h12, (void*)&cnt, (void*)&outp };
  hipLaunchCooperativeKernel((void*)lstm_kernel, dim3(256), dim3(512), args, 0, stream);
}